// Round 7
// baseline (217.785 us; speedup 1.0000x reference)
//
#include <hip/hip_runtime.h>
#include <stdint.h>

#define NB 4096   // query rows
#define NM 8192   // memory rows
#define ND 1024   // feature dim

typedef __attribute__((ext_vector_type(8))) short bf16x8;
typedef __attribute__((ext_vector_type(4))) float f32x4;
typedef __attribute__((ext_vector_type(8))) unsigned short u16x8;

static __device__ __forceinline__ unsigned short f2bf(float f) {
  union { float f; uint32_t u; } v; v.f = f;
  uint32_t u = v.u;
  u += 0x7fffu + ((u >> 16) & 1u);   // RNE
  return (unsigned short)(u >> 16);
}
static __device__ __forceinline__ float bf2f(unsigned short b) {
  union { uint32_t u; float f; } v; v.u = ((uint32_t)b) << 16; return v.f;
}

static __device__ __forceinline__ void gload_lds16(const void* g, void* l) {
  __builtin_amdgcn_global_load_lds(
      (__attribute__((address_space(1))) void*)g,
      (__attribute__((address_space(3))) void*)l, 16, 0, 0);
}

#define BAR()   __builtin_amdgcn_s_barrier()
#define LGKM0() asm volatile("s_waitcnt lgkmcnt(0)" ::: "memory")
#define VMC8()  asm volatile("s_waitcnt vmcnt(8)" ::: "memory")
#define VMC0()  asm volatile("s_waitcnt vmcnt(0)" ::: "memory")

// ---- L2-normalize rows of x [rows x 1024] fp32 -> bf16 out -----------------
__global__ void nrm_kernel(const float* __restrict__ x, unsigned short* __restrict__ out) {
  const int row = blockIdx.x, t = threadIdx.x;
  const float4 v = ((const float4*)(x + (size_t)row * ND))[t];
  float ss = v.x * v.x + v.y * v.y + v.z * v.z + v.w * v.w;
  #pragma unroll
  for (int o = 32; o > 0; o >>= 1) ss += __shfl_xor(ss, o);
  __shared__ float red[4];
  if ((t & 63) == 0) red[t >> 6] = ss;
  __syncthreads();
  ss = (red[0] + red[1]) + (red[2] + red[3]);
  const float sc = 1.0f / fmaxf(sqrtf(ss), 1e-12f);
  ushort4 o4;
  o4.x = f2bf(v.x * sc); o4.y = f2bf(v.y * sc);
  o4.z = f2bf(v.z * sc); o4.w = f2bf(v.w * sc);
  ((ushort4*)(out + (size_t)row * ND))[t] = o4;
}

// ---- transpose memn [8192x1024] bf16 -> memt [1024x8192] bf16 --------------
__global__ void tr_kernel(const unsigned short* __restrict__ memn, unsigned short* __restrict__ memt) {
  __shared__ unsigned short Ts[64][66];
  const int t = threadIdx.x;
  const int d0 = blockIdx.x * 64, m0 = blockIdx.y * 64;
  #pragma unroll
  for (int r = 0; r < 2; ++r) {
    const int lrow = r * 32 + (t >> 3);
    const int lcol = (t & 7) * 8;
    u16x8 v = *(const u16x8*)(memn + (size_t)(m0 + lrow) * ND + d0 + lcol);
    #pragma unroll
    for (int j = 0; j < 8; ++j) Ts[lcol + j][lrow] = v[j];
  }
  __syncthreads();
  #pragma unroll
  for (int r = 0; r < 2; ++r) {
    const int orow = r * 32 + (t >> 3);
    const int ocol = (t & 7) * 8;
    u16x8 o;
    #pragma unroll
    for (int j = 0; j < 8; ++j) o[j] = Ts[orow][ocol + j];
    *(u16x8*)(memt + (size_t)(d0 + orow) * NM + m0 + ocol) = o;
  }
}

// ======================= 256x256 8-phase GEMM (T2+T3+T4+T5) ==================
// C[M,N] = A[M,K] * B[N,K]^T (both bf16 row-major, ld = K stride).
// 512 thr = 8 waves (2M x 4N), per-wave 128x64 out, BK=64, dbuf LDS 128 KiB.
// Swizzle: phys_cb = cb ^ ((row&7)<<4), pre-swizzled global SOURCE for
// global_load_lds (linear dest, rule #21) + swizzled ds_read addrs.
// FRAGMENT ROW MAP (race fix, r5): A row = m*32 + wr*16 + lr,
// B row = nf*64 + wc*16 + lr -> alo reads A-h0 only, ahi A-h1, blo B-h0,
// bhi B-h1, for EVERY wave.
// Quadrant order ph1(alo*blo) ph2(ahi*blo) ph3(ahi*bhi) ph4(alo*bhi):
//   region last LDS-read: A-h0 ph1, B-h0 ph1, A-h1 ph2, B-h1 ph3
//   stage (T+2):          ph2: A-h0 + B-h0, ph3: A-h1, ph4: B-h1
// Each stage >=1 end-barrier after its region's last read -> race-free.
// Single vmcnt(8) at ph4 end drains T+1's 8 loads, leaves T+2's in flight.
// r7: NO sched_barrier(0) anywhere (m141 failure mode) — compiler schedules
// within barrier windows; barriers/vmcnt/lgkm preserve the race discipline.
// MODE 0: fp32 C partials (split-K).  MODE 1: E=exp(C) bf16 + psum row-sums.
template<int MODE>
__global__ __launch_bounds__(512, 2) void gemm8p(
    const unsigned short* __restrict__ A, const unsigned short* __restrict__ B,
    void* __restrict__ Cv, float* __restrict__ psum,
    int ld, int ldc, int mt, int tps, int kchunk, unsigned long long cstride)
{
  extern __shared__ char smem[];   // [buf][A 32K | B 32K] x2 = 128 KiB
  const int t = threadIdx.x;
  const int w = t >> 6, l = t & 63;
  const int wr = w >> 2, wc = w & 3;
  const int nwg = gridDim.x, cpx = nwg >> 3;
  const int id = (blockIdx.x & 7) * cpx + (blockIdx.x >> 3);  // XCD swizzle
  const int ksp = id / tps, rem = id % tps;
  const int brow = rem % mt, bcol = rem / mt;
  const int k0 = ksp * kchunk;
  const int nt = kchunk >> 6;          // K-tiles (even)

  const int srow = l >> 3;                       // staging row-in-8-group
  const int scol = ((l & 7) ^ srow) << 3;        // pre-swizzled global col
  const int lr = l & 15, lhi = l >> 4;
  const int swz = (l & 7) << 4;
  const int cbk0 = (lhi * 16) ^ swz;
  const int cbk1 = (64 + lhi * 16) ^ swz;
  const int aoffr = (wr * 16 + lr) * 128;        // + m*4096
  const int boffr = (wc * 16 + lr) * 128;        // + nf*8192

  const unsigned short* Ab = A + (size_t)(brow * 256 + w * 8 + srow) * ld + k0 + scol;
  const unsigned short* Bb = B + (size_t)(bcol * 256 + w * 8 + srow) * ld + k0 + scol;

  auto stageA = [&](int p, int h, int tau) {
    const int kt = (tau < nt ? tau : nt - 1) << 6;
    const unsigned short* g = Ab + (size_t)(h * 128) * ld + kt;
    char* d = smem + p * 65536 + h * 16384 + w * 1024;
    gload_lds16(g, d);
    gload_lds16(g + (size_t)64 * ld, d + 8192);
  };
  auto stageB = [&](int p, int h, int tau) {
    const int kt = (tau < nt ? tau : nt - 1) << 6;
    const unsigned short* g = Bb + (size_t)(h * 128) * ld + kt;
    char* d = smem + p * 65536 + 32768 + h * 16384 + w * 1024;
    gload_lds16(g, d);
    gload_lds16(g + (size_t)64 * ld, d + 8192);
  };
  auto ldA = [&](int p, int m, int kk) -> bf16x8 {   // A row m*32+wr*16+lr
    return *(const bf16x8*)(smem + p * 65536 + m * 4096 + aoffr + (kk ? cbk1 : cbk0));
  };
  auto ldB = [&](int p, int nf, int kk) -> bf16x8 {  // B row nf*64+wc*16+lr
    return *(const bf16x8*)(smem + p * 65536 + 32768 + nf * 8192 + boffr + (kk ? cbk1 : cbk0));
  };

  f32x4 acc[8][4] = {};

  // prologue: tiles 0 and 1 fully staged; drain tile0, leave tile1 in flight.
  stageB(0, 0, 0); stageB(0, 1, 0); stageA(0, 0, 0); stageA(0, 1, 0);
  stageB(1, 0, 1); stageB(1, 1, 1); stageA(1, 0, 1); stageA(1, 1, 1);
  VMC8();
  BAR();

  auto tile_body = [&](int p, int tau2) {
    bf16x8 alo[4][2], ahi[4][2], blo[2][2], bhi[2][2];
    // ---- ph1: (alo, blo) -> acc[m][n]; 12 ds_reads, no stage
    #pragma unroll
    for (int m = 0; m < 4; ++m) { alo[m][0] = ldA(p, m, 0); alo[m][1] = ldA(p, m, 1); }
    #pragma unroll
    for (int n = 0; n < 2; ++n) { blo[n][0] = ldB(p, n, 0); blo[n][1] = ldB(p, n, 1); }
    BAR(); LGKM0();
    __builtin_amdgcn_s_setprio(1);
    #pragma unroll
    for (int m = 0; m < 4; ++m)
      #pragma unroll
      for (int n = 0; n < 2; ++n)
        #pragma unroll
        for (int kk = 0; kk < 2; ++kk)
          acc[m][n] = __builtin_amdgcn_mfma_f32_16x16x32_bf16(alo[m][kk], blo[n][kk], acc[m][n], 0, 0, 0);
    __builtin_amdgcn_s_setprio(0);
    BAR();
    // ---- ph2: (ahi, blo) -> acc[4+m][n]; 8 ds_reads; stage A-h0 + B-h0 (T+2)
    #pragma unroll
    for (int m = 0; m < 4; ++m) { ahi[m][0] = ldA(p, 4 + m, 0); ahi[m][1] = ldA(p, 4 + m, 1); }
    stageA(p, 0, tau2); stageB(p, 0, tau2);
    BAR(); LGKM0();
    __builtin_amdgcn_s_setprio(1);
    #pragma unroll
    for (int m = 0; m < 4; ++m)
      #pragma unroll
      for (int n = 0; n < 2; ++n)
        #pragma unroll
        for (int kk = 0; kk < 2; ++kk)
          acc[4 + m][n] = __builtin_amdgcn_mfma_f32_16x16x32_bf16(ahi[m][kk], blo[n][kk], acc[4 + m][n], 0, 0, 0);
    __builtin_amdgcn_s_setprio(0);
    BAR();
    // ---- ph3: (ahi, bhi) -> acc[4+m][2+n]; 4 ds_reads; stage A-h1 (T+2)
    #pragma unroll
    for (int n = 0; n < 2; ++n) { bhi[n][0] = ldB(p, 2 + n, 0); bhi[n][1] = ldB(p, 2 + n, 1); }
    stageA(p, 1, tau2);
    BAR(); LGKM0();
    __builtin_amdgcn_s_setprio(1);
    #pragma unroll
    for (int m = 0; m < 4; ++m)
      #pragma unroll
      for (int n = 0; n < 2; ++n)
        #pragma unroll
        for (int kk = 0; kk < 2; ++kk)
          acc[4 + m][2 + n] = __builtin_amdgcn_mfma_f32_16x16x32_bf16(ahi[m][kk], bhi[n][kk], acc[4 + m][2 + n], 0, 0, 0);
    __builtin_amdgcn_s_setprio(0);
    BAR();
    // ---- ph4: (alo, bhi) -> acc[m][2+n]; 0 ds_reads; stage B-h1; vmcnt drain
    stageB(p, 1, tau2);
    BAR();
    __builtin_amdgcn_s_setprio(1);
    #pragma unroll
    for (int m = 0; m < 4; ++m)
      #pragma unroll
      for (int n = 0; n < 2; ++n)
        #pragma unroll
        for (int kk = 0; kk < 2; ++kk)
          acc[m][2 + n] = __builtin_amdgcn_mfma_f32_16x16x32_bf16(alo[m][kk], bhi[n][kk], acc[m][2 + n], 0, 0, 0);
    __builtin_amdgcn_s_setprio(0);
    VMC8();          // drains tile T+1 (issued last body)
    BAR();
  };

  const int niter = nt >> 1;
  for (int i = 0; i < niter; ++i) {
    tile_body(0, 2 * i + 2);
    tile_body(1, 2 * i + 3);
  }

  // epilogue: C row = brow*256 + m*32 + wr*16 + lhi*4 + j,
  //           C col = bcol*256 + n*64 + wc*16 + lr     [m89/m91 C/D map]
  const int crow0 = brow * 256 + wr * 16 + lhi * 4;
  const int ccol0 = bcol * 256 + wc * 16 + lr;
  if constexpr (MODE == 1) {
    // E = exp(sim) bf16 + per-block row-sum partials (deterministic)
    unsigned short* Cp = (unsigned short*)Cv;
    float rs[8][4];
    #pragma unroll
    for (int m = 0; m < 8; ++m)
      #pragma unroll
      for (int j = 0; j < 4; ++j) rs[m][j] = 0.f;
    #pragma unroll
    for (int m = 0; m < 8; ++m)
      #pragma unroll
      for (int n = 0; n < 4; ++n)
        #pragma unroll
        for (int j = 0; j < 4; ++j) {
          const float e = __expf(acc[m][n][j]);
          rs[m][j] += e;
          Cp[(size_t)(crow0 + m * 32 + j) * ldc + ccol0 + n * 64] = f2bf(e);
        }
    // 16-lane (lr) reduce -> lanes lr==0 hold this wave's 64-col sums
    #pragma unroll
    for (int m = 0; m < 8; ++m)
      #pragma unroll
      for (int j = 0; j < 4; ++j)
        #pragma unroll
        for (int o = 1; o < 16; o <<= 1) rs[m][j] += __shfl_xor(rs[m][j], o);
    VMC0();            // in-flight dummy stages still write smem
    __syncthreads();
    float* ls = (float*)smem;   // [wc][256 rows] = 4 KiB (buffer-0 region)
    if (lr == 0) {
      #pragma unroll
      for (int m = 0; m < 8; ++m)
        #pragma unroll
        for (int j = 0; j < 4; ++j)
          ls[wc * 256 + wr * 16 + m * 32 + lhi * 4 + j] = rs[m][j];
    }
    __syncthreads();
    if (t < 256) {
      const float s4 = ls[t] + ls[256 + t] + ls[512 + t] + ls[768 + t];
      psum[(size_t)bcol * NB + brow * 256 + t] = s4;
    }
  } else {
    float* Cp = (float*)Cv + (unsigned long long)ksp * cstride;
    #pragma unroll
    for (int m = 0; m < 8; ++m)
      #pragma unroll
      for (int n = 0; n < 4; ++n)
        #pragma unroll
        for (int j = 0; j < 4; ++j)
          Cp[(size_t)(crow0 + m * 32 + j) * ldc + ccol0 + n * 64] = acc[m][n][j];
  }
}

// ---- scale: attn = E / s, s = sum of 32 col-block partials; also 1/s -------
__global__ void scale_kernel(const unsigned short* __restrict__ E,
                             const float* __restrict__ psum,
                             float* __restrict__ attn, float* __restrict__ sinv) {
  const int row = blockIdx.x, t = threadIdx.x;   // 256 thr
  __shared__ float sh;
  if (t < 64) {
    float p = (t < 32) ? psum[(size_t)t * NB + row] : 0.f;
    #pragma unroll
    for (int o = 16; o > 0; o >>= 1) p += __shfl_xor(p, o);
    if (t == 0) { sh = p; sinv[row] = 1.0f / p; }
  }
  __syncthreads();
  const float inv = 1.0f / sh;
  const unsigned short* erow = E + (size_t)row * NM;
  float* arow = attn + (size_t)row * NM;
  #pragma unroll
  for (int i = 0; i < 4; ++i) {
    u16x8 bv = ((const u16x8*)erow)[i * 256 + t];
    float4 f0, f1;
    #pragma unroll
    for (int j = 0; j < 8; ++j) {
      const float a = bf2f(bv[j]) * inv;
      if (j < 4) (&f0.x)[j] = a; else (&f1.x)[j - 4] = a;
    }
    const int e = (i * 256 + t) * 8;
    *(float4*)(arow + e) = f0;
    *(float4*)(arow + e + 4) = f1;
  }
}

// ---- reduce partials: mf = (sum_k part[k]) * sinv[row], S = 4 --------------
__global__ void reduce_kernel(const float4* __restrict__ part, float4* __restrict__ mf,
                              const float* __restrict__ sinv) {
  const size_t n4 = (size_t)NB * ND / 4;
  for (size_t i = (size_t)blockIdx.x * blockDim.x + threadIdx.x; i < n4;
       i += (size_t)gridDim.x * blockDim.x) {
    const float is = sinv[i >> 8];   // 256 float4 per row
    float4 s = part[i];
    #pragma unroll
    for (int k = 1; k < 4; ++k) {
      float4 p = part[(size_t)k * n4 + i];
      s.x += p.x; s.y += p.y; s.z += p.z; s.w += p.w;
    }
    s.x *= is; s.y *= is; s.z *= is; s.w *= is;
    mf[i] = s;
  }
}

extern "C" void kernel_launch(void* const* d_in, const int* in_sizes, int n_in,
                              void* d_out, int out_size, void* d_ws, size_t ws_size,
                              hipStream_t stream) {
  const float* q   = (const float*)d_in[0];
  const float* mem = (const float*)d_in[1];
  float* mf   = (float*)d_out;                       // [4096 x 1024]
  float* attn = (float*)d_out + (size_t)NB * ND;     // [4096 x 8192]
  char* ws = (char*)d_ws;
  unsigned short* qn   = (unsigned short*)(ws);                        // 8 MiB
  unsigned short* memn = (unsigned short*)(ws + ((size_t)8  << 20));   // 16 MiB
  unsigned short* memt = (unsigned short*)(ws + ((size_t)24 << 20));   // 16 MiB
  unsigned short* E    = (unsigned short*)(ws + ((size_t)40 << 20));   // 64 MiB
  float* psum          = (float*)(ws + ((size_t)104 << 20));           // 512 KiB
  float* sinv          = (float*)(ws + ((size_t)104 << 20) + (512 << 10)); // 16 KiB
  float* part          = (float*)(ws + ((size_t)105 << 20));           // 64 MiB

  hipFuncSetAttribute((const void*)gemm8p<1>,
                      hipFuncAttributeMaxDynamicSharedMemorySize, 131072);
  hipFuncSetAttribute((const void*)gemm8p<0>,
                      hipFuncAttributeMaxDynamicSharedMemorySize, 131072);

  hipLaunchKernelGGL(nrm_kernel, dim3(NM), dim3(256), 0, stream, mem, memn);
  hipLaunchKernelGGL(nrm_kernel, dim3(NB), dim3(256), 0, stream, q, qn);
  hipLaunchKernelGGL(tr_kernel, dim3(ND / 64, NM / 64), dim3(256), 0, stream, memn, memt);

  // E = exp(qn * memn^T) bf16 + psum : M=4096, N=8192, K=1024; 512 tiles.
  hipLaunchKernelGGL((gemm8p<1>), dim3((NB / 256) * (NM / 256)), dim3(512), 131072, stream,
                     qn, memn, (void*)E, psum, ND, NM, NB / 256,
                     (NB / 256) * (NM / 256), ND, 0ULL);

  // attn = E / s (fp32 out) + sinv
  hipLaunchKernelGGL(scale_kernel, dim3(NB), dim3(256), 0, stream, E, psum, attn, sinv);

  // part[k] = E * memt^T (k-slice) : M=4096, N=1024, K=8192, S=4 (kchunk 2048)
  const int tps = (NB / 256) * (ND / 256);   // 64
  hipLaunchKernelGGL((gemm8p<0>), dim3(tps * 4), dim3(512), 131072, stream,
                     E, memt, (void*)part, (float*)nullptr, NM, ND, NB / 256, tps, NM / 4,
                     (unsigned long long)NB * ND);
  hipLaunchKernelGGL(reduce_kernel, dim3(2048), dim3(256), 0, stream,
                     (const float4*)part, (float4*)mf, sinv);
}

// Round 8
// 217.538 us; speedup vs baseline: 1.0011x; 1.0011x over previous
//
#include <hip/hip_runtime.h>
#include <stdint.h>

#define NB 4096   // query rows
#define NM 8192   // memory rows
#define ND 1024   // feature dim

typedef __attribute__((ext_vector_type(8))) short bf16x8;
typedef __attribute__((ext_vector_type(4))) float f32x4;
typedef __attribute__((ext_vector_type(8))) unsigned short u16x8;

static __device__ __forceinline__ unsigned short f2bf(float f) {
  union { float f; uint32_t u; } v; v.f = f;
  uint32_t u = v.u;
  u += 0x7fffu + ((u >> 16) & 1u);   // RNE
  return (unsigned short)(u >> 16);
}
static __device__ __forceinline__ float bf2f(unsigned short b) {
  union { uint32_t u; float f; } v; v.u = ((uint32_t)b) << 16; return v.f;
}

static __device__ __forceinline__ void gload_lds16(const void* g, void* l) {
  __builtin_amdgcn_global_load_lds(
      (__attribute__((address_space(1))) void*)g,
      (__attribute__((address_space(3))) void*)l, 16, 0, 0);
}

#define BAR()   __builtin_amdgcn_s_barrier()
#define LGKM0() asm volatile("s_waitcnt lgkmcnt(0)" ::: "memory")
#define VMC8()  asm volatile("s_waitcnt vmcnt(8)" ::: "memory")
#define VMC0()  asm volatile("s_waitcnt vmcnt(0)" ::: "memory")

// ---- L2-normalize rows of x [rows x 1024] fp32 -> bf16 out -----------------
__global__ void nrm_kernel(const float* __restrict__ x, unsigned short* __restrict__ out) {
  const int row = blockIdx.x, t = threadIdx.x;
  const float4 v = ((const float4*)(x + (size_t)row * ND))[t];
  float ss = v.x * v.x + v.y * v.y + v.z * v.z + v.w * v.w;
  #pragma unroll
  for (int o = 32; o > 0; o >>= 1) ss += __shfl_xor(ss, o);
  __shared__ float red[4];
  if ((t & 63) == 0) red[t >> 6] = ss;
  __syncthreads();
  ss = (red[0] + red[1]) + (red[2] + red[3]);
  const float sc = 1.0f / fmaxf(sqrtf(ss), 1e-12f);
  ushort4 o4;
  o4.x = f2bf(v.x * sc); o4.y = f2bf(v.y * sc);
  o4.z = f2bf(v.z * sc); o4.w = f2bf(v.w * sc);
  ((ushort4*)(out + (size_t)row * ND))[t] = o4;
}

// ---- transpose memn [8192x1024] bf16 -> memt [1024x8192] bf16 --------------
__global__ void tr_kernel(const unsigned short* __restrict__ memn, unsigned short* __restrict__ memt) {
  __shared__ unsigned short Ts[64][66];
  const int t = threadIdx.x;
  const int d0 = blockIdx.x * 64, m0 = blockIdx.y * 64;
  #pragma unroll
  for (int r = 0; r < 2; ++r) {
    const int lrow = r * 32 + (t >> 3);
    const int lcol = (t & 7) * 8;
    u16x8 v = *(const u16x8*)(memn + (size_t)(m0 + lrow) * ND + d0 + lcol);
    #pragma unroll
    for (int j = 0; j < 8; ++j) Ts[lcol + j][lrow] = v[j];
  }
  __syncthreads();
  #pragma unroll
  for (int r = 0; r < 2; ++r) {
    const int orow = r * 32 + (t >> 3);
    const int ocol = (t & 7) * 8;
    u16x8 o;
    #pragma unroll
    for (int j = 0; j < 8; ++j) o[j] = Ts[orow][ocol + j];
    *(u16x8*)(memt + (size_t)(d0 + orow) * NM + m0 + ocol) = o;
  }
}

// ======================= 256x256 8-phase GEMM (T2+T3+T4+T5) ==================
// C[M,N] = A[M,K] * B[N,K]^T (both bf16 row-major, ld = K stride).
// 512 thr = 8 waves (2M x 4N), per-wave 128x64 out, BK=64, dbuf LDS 128 KiB.
// Swizzle: phys_cb = cb ^ ((row&7)<<4), pre-swizzled global SOURCE for
// global_load_lds (linear dest, rule #21) + swizzled ds_read addrs.
// FRAGMENT ROW MAP (race fix, r5): A row = m*32 + wr*16 + lr,
// B row = nf*64 + wc*16 + lr -> alo reads A-h0 only, ahi A-h1, blo B-h0,
// bhi B-h1, for EVERY wave.
// Quadrant order ph1(alo*blo) ph2(ahi*blo) ph3(ahi*bhi) ph4(alo*bhi):
//   region last LDS-read: A-h0 ph1, B-h0 ph1, A-h1 ph2, B-h1 ph3
//   stage (T+2):          ph2: A-h0 + B-h0, ph3: A-h1, ph4: B-h1
// Each stage >=1 end-barrier after its region's last read -> race-free.
// Single vmcnt(8) at ph4 end drains T+1's 8 loads, leaves T+2's in flight.
// r8: MFMA clusters are kk-OUTER (8 independent acc targets back-to-back,
// dep distance 8) so the wave issues its 16 MFMAs without RAW stalls,
// reaches the end barrier early, and the next phase's ds_reads overlap the
// matrix-pipe drain. (r7's (m,n,kk) order chained every adjacent pair.)
// MODE 0: fp32 C partials (split-K).  MODE 1: E=exp(C) bf16 + psum row-sums.
template<int MODE>
__global__ __launch_bounds__(512, 2) void gemm8p(
    const unsigned short* __restrict__ A, const unsigned short* __restrict__ B,
    void* __restrict__ Cv, float* __restrict__ psum,
    int ld, int ldc, int mt, int tps, int kchunk, unsigned long long cstride)
{
  extern __shared__ char smem[];   // [buf][A 32K | B 32K] x2 = 128 KiB
  const int t = threadIdx.x;
  const int w = t >> 6, l = t & 63;
  const int wr = w >> 2, wc = w & 3;
  const int nwg = gridDim.x, cpx = nwg >> 3;
  const int id = (blockIdx.x & 7) * cpx + (blockIdx.x >> 3);  // XCD swizzle
  const int ksp = id / tps, rem = id % tps;
  const int brow = rem % mt, bcol = rem / mt;
  const int k0 = ksp * kchunk;
  const int nt = kchunk >> 6;          // K-tiles (even)

  const int srow = l >> 3;                       // staging row-in-8-group
  const int scol = ((l & 7) ^ srow) << 3;        // pre-swizzled global col
  const int lr = l & 15, lhi = l >> 4;
  const int swz = (l & 7) << 4;
  const int cbk0 = (lhi * 16) ^ swz;
  const int cbk1 = (64 + lhi * 16) ^ swz;
  const int aoffr = (wr * 16 + lr) * 128;        // + m*4096
  const int boffr = (wc * 16 + lr) * 128;        // + nf*8192

  const unsigned short* Ab = A + (size_t)(brow * 256 + w * 8 + srow) * ld + k0 + scol;
  const unsigned short* Bb = B + (size_t)(bcol * 256 + w * 8 + srow) * ld + k0 + scol;

  auto stageA = [&](int p, int h, int tau) {
    const int kt = (tau < nt ? tau : nt - 1) << 6;
    const unsigned short* g = Ab + (size_t)(h * 128) * ld + kt;
    char* d = smem + p * 65536 + h * 16384 + w * 1024;
    gload_lds16(g, d);
    gload_lds16(g + (size_t)64 * ld, d + 8192);
  };
  auto stageB = [&](int p, int h, int tau) {
    const int kt = (tau < nt ? tau : nt - 1) << 6;
    const unsigned short* g = Bb + (size_t)(h * 128) * ld + kt;
    char* d = smem + p * 65536 + 32768 + h * 16384 + w * 1024;
    gload_lds16(g, d);
    gload_lds16(g + (size_t)64 * ld, d + 8192);
  };
  auto ldA = [&](int p, int m, int kk) -> bf16x8 {   // A row m*32+wr*16+lr
    return *(const bf16x8*)(smem + p * 65536 + m * 4096 + aoffr + (kk ? cbk1 : cbk0));
  };
  auto ldB = [&](int p, int nf, int kk) -> bf16x8 {  // B row nf*64+wc*16+lr
    return *(const bf16x8*)(smem + p * 65536 + 32768 + nf * 8192 + boffr + (kk ? cbk1 : cbk0));
  };

  f32x4 acc[8][4] = {};

  // prologue: tiles 0 and 1 fully staged; drain tile0, leave tile1 in flight.
  stageB(0, 0, 0); stageB(0, 1, 0); stageA(0, 0, 0); stageA(0, 1, 0);
  stageB(1, 0, 1); stageB(1, 1, 1); stageA(1, 0, 1); stageA(1, 1, 1);
  VMC8();
  BAR();

  auto tile_body = [&](int p, int tau2) {
    bf16x8 alo[4][2], ahi[4][2], blo[2][2], bhi[2][2];
    // ---- ph1: (alo, blo) -> acc[m][n]; 12 ds_reads, no stage
    #pragma unroll
    for (int m = 0; m < 4; ++m) { alo[m][0] = ldA(p, m, 0); alo[m][1] = ldA(p, m, 1); }
    #pragma unroll
    for (int n = 0; n < 2; ++n) { blo[n][0] = ldB(p, n, 0); blo[n][1] = ldB(p, n, 1); }
    BAR(); LGKM0();
    __builtin_amdgcn_s_setprio(1);
    #pragma unroll
    for (int kk = 0; kk < 2; ++kk)
      #pragma unroll
      for (int m = 0; m < 4; ++m)
        #pragma unroll
        for (int n = 0; n < 2; ++n)
          acc[m][n] = __builtin_amdgcn_mfma_f32_16x16x32_bf16(alo[m][kk], blo[n][kk], acc[m][n], 0, 0, 0);
    __builtin_amdgcn_s_setprio(0);
    BAR();
    // ---- ph2: (ahi, blo) -> acc[4+m][n]; 8 ds_reads; stage A-h0 + B-h0 (T+2)
    #pragma unroll
    for (int m = 0; m < 4; ++m) { ahi[m][0] = ldA(p, 4 + m, 0); ahi[m][1] = ldA(p, 4 + m, 1); }
    stageA(p, 0, tau2); stageB(p, 0, tau2);
    BAR(); LGKM0();
    __builtin_amdgcn_s_setprio(1);
    #pragma unroll
    for (int kk = 0; kk < 2; ++kk)
      #pragma unroll
      for (int m = 0; m < 4; ++m)
        #pragma unroll
        for (int n = 0; n < 2; ++n)
          acc[4 + m][n] = __builtin_amdgcn_mfma_f32_16x16x32_bf16(ahi[m][kk], blo[n][kk], acc[4 + m][n], 0, 0, 0);
    __builtin_amdgcn_s_setprio(0);
    BAR();
    // ---- ph3: (ahi, bhi) -> acc[4+m][2+n]; 4 ds_reads; stage A-h1 (T+2)
    #pragma unroll
    for (int n = 0; n < 2; ++n) { bhi[n][0] = ldB(p, 2 + n, 0); bhi[n][1] = ldB(p, 2 + n, 1); }
    stageA(p, 1, tau2);
    BAR(); LGKM0();
    __builtin_amdgcn_s_setprio(1);
    #pragma unroll
    for (int kk = 0; kk < 2; ++kk)
      #pragma unroll
      for (int m = 0; m < 4; ++m)
        #pragma unroll
        for (int n = 0; n < 2; ++n)
          acc[4 + m][2 + n] = __builtin_amdgcn_mfma_f32_16x16x32_bf16(ahi[m][kk], bhi[n][kk], acc[4 + m][2 + n], 0, 0, 0);
    __builtin_amdgcn_s_setprio(0);
    BAR();
    // ---- ph4: (alo, bhi) -> acc[m][2+n]; 0 ds_reads; stage B-h1; vmcnt drain
    stageB(p, 1, tau2);
    BAR();
    __builtin_amdgcn_s_setprio(1);
    #pragma unroll
    for (int kk = 0; kk < 2; ++kk)
      #pragma unroll
      for (int m = 0; m < 4; ++m)
        #pragma unroll
        for (int n = 0; n < 2; ++n)
          acc[m][2 + n] = __builtin_amdgcn_mfma_f32_16x16x32_bf16(alo[m][kk], bhi[n][kk], acc[m][2 + n], 0, 0, 0);
    __builtin_amdgcn_s_setprio(0);
    VMC8();          // drains tile T+1 (issued last body)
    BAR();
  };

  const int niter = nt >> 1;
  for (int i = 0; i < niter; ++i) {
    tile_body(0, 2 * i + 2);
    tile_body(1, 2 * i + 3);
  }

  // epilogue: C row = brow*256 + m*32 + wr*16 + lhi*4 + j,
  //           C col = bcol*256 + n*64 + wc*16 + lr     [m89/m91 C/D map]
  const int crow0 = brow * 256 + wr * 16 + lhi * 4;
  const int ccol0 = bcol * 256 + wc * 16 + lr;
  if constexpr (MODE == 1) {
    // E = exp(sim) bf16 + per-block row-sum partials (deterministic)
    unsigned short* Cp = (unsigned short*)Cv;
    float rs[8][4];
    #pragma unroll
    for (int m = 0; m < 8; ++m)
      #pragma unroll
      for (int j = 0; j < 4; ++j) rs[m][j] = 0.f;
    #pragma unroll
    for (int m = 0; m < 8; ++m)
      #pragma unroll
      for (int n = 0; n < 4; ++n)
        #pragma unroll
        for (int j = 0; j < 4; ++j) {
          const float e = __expf(acc[m][n][j]);
          rs[m][j] += e;
          Cp[(size_t)(crow0 + m * 32 + j) * ldc + ccol0 + n * 64] = f2bf(e);
        }
    // 16-lane (lr) reduce -> lanes lr==0 hold this wave's 64-col sums
    #pragma unroll
    for (int m = 0; m < 8; ++m)
      #pragma unroll
      for (int j = 0; j < 4; ++j)
        #pragma unroll
        for (int o = 1; o < 16; o <<= 1) rs[m][j] += __shfl_xor(rs[m][j], o);
    VMC0();            // in-flight dummy stages still write smem
    __syncthreads();
    float* ls = (float*)smem;   // [wc][256 rows] = 4 KiB (buffer-0 region)
    if (lr == 0) {
      #pragma unroll
      for (int m = 0; m < 8; ++m)
        #pragma unroll
        for (int j = 0; j < 4; ++j)
          ls[wc * 256 + wr * 16 + m * 32 + lhi * 4 + j] = rs[m][j];
    }
    __syncthreads();
    if (t < 256) {
      const float s4 = ls[t] + ls[256 + t] + ls[512 + t] + ls[768 + t];
      psum[(size_t)bcol * NB + brow * 256 + t] = s4;
    }
  } else {
    float* Cp = (float*)Cv + (unsigned long long)ksp * cstride;
    #pragma unroll
    for (int m = 0; m < 8; ++m)
      #pragma unroll
      for (int n = 0; n < 4; ++n)
        #pragma unroll
        for (int j = 0; j < 4; ++j)
          Cp[(size_t)(crow0 + m * 32 + j) * ldc + ccol0 + n * 64] = acc[m][n][j];
  }
}

// ---- scale: attn = E / s, s = sum of 32 col-block partials; also 1/s -------
__global__ void scale_kernel(const unsigned short* __restrict__ E,
                             const float* __restrict__ psum,
                             float* __restrict__ attn, float* __restrict__ sinv) {
  const int row = blockIdx.x, t = threadIdx.x;   // 256 thr
  __shared__ float sh;
  if (t < 64) {
    float p = (t < 32) ? psum[(size_t)t * NB + row] : 0.f;
    #pragma unroll
    for (int o = 16; o > 0; o >>= 1) p += __shfl_xor(p, o);
    if (t == 0) { sh = p; sinv[row] = 1.0f / p; }
  }
  __syncthreads();
  const float inv = 1.0f / sh;
  const unsigned short* erow = E + (size_t)row * NM;
  float* arow = attn + (size_t)row * NM;
  #pragma unroll
  for (int i = 0; i < 4; ++i) {
    u16x8 bv = ((const u16x8*)erow)[i * 256 + t];
    float4 f0, f1;
    #pragma unroll
    for (int j = 0; j < 8; ++j) {
      const float a = bf2f(bv[j]) * inv;
      if (j < 4) (&f0.x)[j] = a; else (&f1.x)[j - 4] = a;
    }
    const int e = (i * 256 + t) * 8;
    *(float4*)(arow + e) = f0;
    *(float4*)(arow + e + 4) = f1;
  }
}

// ---- reduce partials: mf = (sum_k part[k]) * sinv[row], S = 4 --------------
__global__ void reduce_kernel(const float4* __restrict__ part, float4* __restrict__ mf,
                              const float* __restrict__ sinv) {
  const size_t n4 = (size_t)NB * ND / 4;
  for (size_t i = (size_t)blockIdx.x * blockDim.x + threadIdx.x; i < n4;
       i += (size_t)gridDim.x * blockDim.x) {
    const float is = sinv[i >> 8];   // 256 float4 per row
    float4 s = part[i];
    #pragma unroll
    for (int k = 1; k < 4; ++k) {
      float4 p = part[(size_t)k * n4 + i];
      s.x += p.x; s.y += p.y; s.z += p.z; s.w += p.w;
    }
    s.x *= is; s.y *= is; s.z *= is; s.w *= is;
    mf[i] = s;
  }
}

extern "C" void kernel_launch(void* const* d_in, const int* in_sizes, int n_in,
                              void* d_out, int out_size, void* d_ws, size_t ws_size,
                              hipStream_t stream) {
  const float* q   = (const float*)d_in[0];
  const float* mem = (const float*)d_in[1];
  float* mf   = (float*)d_out;                       // [4096 x 1024]
  float* attn = (float*)d_out + (size_t)NB * ND;     // [4096 x 8192]
  char* ws = (char*)d_ws;
  unsigned short* qn   = (unsigned short*)(ws);                        // 8 MiB
  unsigned short* memn = (unsigned short*)(ws + ((size_t)8  << 20));   // 16 MiB
  unsigned short* memt = (unsigned short*)(ws + ((size_t)24 << 20));   // 16 MiB
  unsigned short* E    = (unsigned short*)(ws + ((size_t)40 << 20));   // 64 MiB
  float* psum          = (float*)(ws + ((size_t)104 << 20));           // 512 KiB
  float* sinv          = (float*)(ws + ((size_t)104 << 20) + (512 << 10)); // 16 KiB
  float* part          = (float*)(ws + ((size_t)105 << 20));           // 64 MiB

  hipFuncSetAttribute((const void*)gemm8p<1>,
                      hipFuncAttributeMaxDynamicSharedMemorySize, 131072);
  hipFuncSetAttribute((const void*)gemm8p<0>,
                      hipFuncAttributeMaxDynamicSharedMemorySize, 131072);

  hipLaunchKernelGGL(nrm_kernel, dim3(NM), dim3(256), 0, stream, mem, memn);
  hipLaunchKernelGGL(nrm_kernel, dim3(NB), dim3(256), 0, stream, q, qn);
  hipLaunchKernelGGL(tr_kernel, dim3(ND / 64, NM / 64), dim3(256), 0, stream, memn, memt);

  // E = exp(qn * memn^T) bf16 + psum : M=4096, N=8192, K=1024; 512 tiles.
  hipLaunchKernelGGL((gemm8p<1>), dim3((NB / 256) * (NM / 256)), dim3(512), 131072, stream,
                     qn, memn, (void*)E, psum, ND, NM, NB / 256,
                     (NB / 256) * (NM / 256), ND, 0ULL);

  // attn = E / s (fp32 out) + sinv
  hipLaunchKernelGGL(scale_kernel, dim3(NB), dim3(256), 0, stream, E, psum, attn, sinv);

  // part[k] = E * memt^T (k-slice) : M=4096, N=1024, K=8192, S=4 (kchunk 2048)
  const int tps = (NB / 256) * (ND / 256);   // 64
  hipLaunchKernelGGL((gemm8p<0>), dim3(tps * 4), dim3(512), 131072, stream,
                     E, memt, (void*)part, (float*)nullptr, NM, ND, NB / 256, tps, NM / 4,
                     (unsigned long long)NB * ND);
  hipLaunchKernelGGL(reduce_kernel, dim3(2048), dim3(256), 0, stream,
                     (const float4*)part, (float4*)mf, sinv);
}

// Round 9
// 208.109 us; speedup vs baseline: 1.0465x; 1.0453x over previous
//
#include <hip/hip_runtime.h>
#include <stdint.h>

#define NB 4096   // query rows
#define NM 8192   // memory rows
#define ND 1024   // feature dim

typedef __attribute__((ext_vector_type(8))) short bf16x8;
typedef __attribute__((ext_vector_type(4))) float f32x4;
typedef __attribute__((ext_vector_type(8))) unsigned short u16x8;

static __device__ __forceinline__ unsigned short f2bf(float f) {
  union { float f; uint32_t u; } v; v.f = f;
  uint32_t u = v.u;
  u += 0x7fffu + ((u >> 16) & 1u);   // RNE
  return (unsigned short)(u >> 16);
}
static __device__ __forceinline__ float bf2f(unsigned short b) {
  union { uint32_t u; float f; } v; v.u = ((uint32_t)b) << 16; return v.f;
}

static __device__ __forceinline__ void gload_lds16(const void* g, void* l) {
  __builtin_amdgcn_global_load_lds(
      (__attribute__((address_space(1))) void*)g,
      (__attribute__((address_space(3))) void*)l, 16, 0, 0);
}

#define BAR()   __builtin_amdgcn_s_barrier()
#define LGKM0() asm volatile("s_waitcnt lgkmcnt(0)" ::: "memory")
#define VMC8()  asm volatile("s_waitcnt vmcnt(8)" ::: "memory")
#define VMC0()  asm volatile("s_waitcnt vmcnt(0)" ::: "memory")

// ---- L2-normalize rows of x [rows x 1024] fp32 -> bf16 out -----------------
__global__ void nrm_kernel(const float* __restrict__ x, unsigned short* __restrict__ out) {
  const int row = blockIdx.x, t = threadIdx.x;
  const float4 v = ((const float4*)(x + (size_t)row * ND))[t];
  float ss = v.x * v.x + v.y * v.y + v.z * v.z + v.w * v.w;
  #pragma unroll
  for (int o = 32; o > 0; o >>= 1) ss += __shfl_xor(ss, o);
  __shared__ float red[4];
  if ((t & 63) == 0) red[t >> 6] = ss;
  __syncthreads();
  ss = (red[0] + red[1]) + (red[2] + red[3]);
  const float sc = 1.0f / fmaxf(sqrtf(ss), 1e-12f);
  ushort4 o4;
  o4.x = f2bf(v.x * sc); o4.y = f2bf(v.y * sc);
  o4.z = f2bf(v.z * sc); o4.w = f2bf(v.w * sc);
  ((ushort4*)(out + (size_t)row * ND))[t] = o4;
}

// ---- transpose memn [8192x1024] bf16 -> memt [1024x8192] bf16 --------------
__global__ void tr_kernel(const unsigned short* __restrict__ memn, unsigned short* __restrict__ memt) {
  __shared__ unsigned short Ts[64][66];
  const int t = threadIdx.x;
  const int d0 = blockIdx.x * 64, m0 = blockIdx.y * 64;
  #pragma unroll
  for (int r = 0; r < 2; ++r) {
    const int lrow = r * 32 + (t >> 3);
    const int lcol = (t & 7) * 8;
    u16x8 v = *(const u16x8*)(memn + (size_t)(m0 + lrow) * ND + d0 + lcol);
    #pragma unroll
    for (int j = 0; j < 8; ++j) Ts[lcol + j][lrow] = v[j];
  }
  __syncthreads();
  #pragma unroll
  for (int r = 0; r < 2; ++r) {
    const int orow = r * 32 + (t >> 3);
    const int ocol = (t & 7) * 8;
    u16x8 o;
    #pragma unroll
    for (int j = 0; j < 8; ++j) o[j] = Ts[orow][ocol + j];
    *(u16x8*)(memt + (size_t)(d0 + orow) * NM + m0 + ocol) = o;
  }
}

// =================== 256x256 GEMM, 2-phase/tile, reads 1 phase ahead ========
// C[M,N] = A[M,K] * B[N,K]^T (both bf16 row-major, ld = K stride).
// 512 thr = 8 waves (2M x 4N), per-wave 128x64 out, BK=64, dbuf LDS 128 KiB.
// Swizzle: phys_cb = cb ^ ((row&7)<<4) on both stage-source and ds_read.
// Fragment rows: A row = m*32 + wr*16 + lr (m=0..7), B row = nf*64 + wc*16 + lr.
// REGISTER PLAN: af[8][2] (A full tile, held across both phases, 64 VGPR),
// b0[2][2]/b1[2][2] (B n-halves, 16 VGPR each). acc 8x4 f32x4.
// SCHEDULE (r9): reads are issued AFTER the MFMA cluster that last consumes
// the registers they overwrite, so the LDS pipe retires them WHILE the
// matrix pipe drains that cluster; their consumer runs a phase later.
//   alpha(T): MFMA(af,b0)->acc[:,0:2] | issue b1(T) reads | lgkm0 | BAR
//   beta(T):  vmcnt(0) [stage(T+1) landed] | BAR | MFMA(af,b1)->acc[:,2:4]
//             | issue af(T+1)+b0(T+1) reads from other buf | stage(T+2)
// Race proof: all reads-of-T complete at alpha's lgkm0 (block-wide via BAR)
// before stage(T+2) writes buf p; buf q readable after vmcnt0+BAR.
// MODE 0: fp32 C partials (split-K).  MODE 1: E=exp(C) bf16 + psum row-sums.
template<int MODE>
__global__ __launch_bounds__(512, 2) void gemm2p(
    const unsigned short* __restrict__ A, const unsigned short* __restrict__ B,
    void* __restrict__ Cv, float* __restrict__ psum,
    int ld, int ldc, int mt, int tps, int kchunk, unsigned long long cstride)
{
  extern __shared__ char smem[];   // [buf][A 32K | B 32K] x2 = 128 KiB
  const int t = threadIdx.x;
  const int w = t >> 6, l = t & 63;
  const int wr = w >> 2, wc = w & 3;
  const int nwg = gridDim.x, cpx = nwg >> 3;
  const int id = (blockIdx.x & 7) * cpx + (blockIdx.x >> 3);  // XCD swizzle
  const int ksp = id / tps, rem = id % tps;
  const int brow = rem % mt, bcol = rem / mt;
  const int k0 = ksp * kchunk;
  const int nt = kchunk >> 6;          // K-tiles

  const int srow = l >> 3;                       // staging row-in-8-group
  const int scol = ((l & 7) ^ srow) << 3;        // pre-swizzled global col
  const int lr = l & 15, lhi = l >> 4;
  const int swz = (l & 7) << 4;
  const int cbk0 = (lhi * 16) ^ swz;
  const int cbk1 = (64 + lhi * 16) ^ swz;
  const int aoffr = (wr * 16 + lr) * 128;        // + m*4096
  const int boffr = (wc * 16 + lr) * 128;        // + nf*8192

  const unsigned short* Ab = A + (size_t)(brow * 256 + w * 8 + srow) * ld + k0 + scol;
  const unsigned short* Bb = B + (size_t)(bcol * 256 + w * 8 + srow) * ld + k0 + scol;

  auto stageT = [&](int p, int tau) {   // full tile stage: 8 gloads/wave
    const int kt = (tau < nt ? tau : nt - 1) << 6;
    const unsigned short* ga = Ab + (size_t)kt;
    const unsigned short* gb = Bb + (size_t)kt;
    char* da = smem + p * 65536 + w * 1024;
    char* db = smem + p * 65536 + 32768 + w * 1024;
    gload_lds16(ga, da);
    gload_lds16(ga + (size_t)64 * ld, da + 8192);
    gload_lds16(ga + (size_t)128 * ld, da + 16384);
    gload_lds16(ga + (size_t)192 * ld, da + 24576);
    gload_lds16(gb, db);
    gload_lds16(gb + (size_t)64 * ld, db + 8192);
    gload_lds16(gb + (size_t)128 * ld, db + 16384);
    gload_lds16(gb + (size_t)192 * ld, db + 24576);
  };
  auto ldA = [&](int p, int m, int kk) -> bf16x8 {   // A row m*32+wr*16+lr
    return *(const bf16x8*)(smem + p * 65536 + m * 4096 + aoffr + (kk ? cbk1 : cbk0));
  };
  auto ldB = [&](int p, int nf, int kk) -> bf16x8 {  // B row nf*64+wc*16+lr
    return *(const bf16x8*)(smem + p * 65536 + 32768 + nf * 8192 + boffr + (kk ? cbk1 : cbk0));
  };

  f32x4 acc[8][4] = {};
  bf16x8 af[8][2], b0[2][2], b1[2][2];

  // prologue: stage tiles 0 and 1; drain tile0; load tile0's af+b0 frags.
  stageT(0, 0);
  stageT(1, 1);
  VMC8();
  BAR();
  #pragma unroll
  for (int m = 0; m < 8; ++m) { af[m][0] = ldA(0, m, 0); af[m][1] = ldA(0, m, 1); }
  #pragma unroll
  for (int n = 0; n < 2; ++n) { b0[n][0] = ldB(0, n, 0); b0[n][1] = ldB(0, n, 1); }

  for (int T = 0; T < nt; ++T) {
    const int p = T & 1, q = p ^ 1;
    // ---- alpha: MFMA (af, b0) -> acc[:, 0:2]; then b1 reads; lgkm0; BAR
    __builtin_amdgcn_s_setprio(1);
    #pragma unroll
    for (int kk = 0; kk < 2; ++kk)
      #pragma unroll
      for (int m = 0; m < 8; ++m)
        #pragma unroll
        for (int n = 0; n < 2; ++n)
          acc[m][n] = __builtin_amdgcn_mfma_f32_16x16x32_bf16(af[m][kk], b0[n][kk], acc[m][n], 0, 0, 0);
    __builtin_amdgcn_s_setprio(0);
    #pragma unroll
    for (int n = 0; n < 2; ++n) { b1[n][0] = ldB(p, 2 + n, 0); b1[n][1] = ldB(p, 2 + n, 1); }
    LGKM0();            // all of this wave's reads-of-T complete
    BAR();              // block-wide: tile T fully read out of LDS
    // ---- beta: stage(T+1) landed; MFMA (af, b1); reads for T+1; stage T+2
    VMC0();             // stage(T+1)'s 8 loads (issued one tile ago) done
    BAR();              // block-wide: buf q fully staged
    __builtin_amdgcn_s_setprio(1);
    #pragma unroll
    for (int kk = 0; kk < 2; ++kk)
      #pragma unroll
      for (int m = 0; m < 8; ++m)
        #pragma unroll
        for (int n = 0; n < 2; ++n)
          acc[m][2 + n] = __builtin_amdgcn_mfma_f32_16x16x32_bf16(af[m][kk], b1[n][kk], acc[m][2 + n], 0, 0, 0);
    __builtin_amdgcn_s_setprio(0);
    // reads for tile T+1 (WAR on the MFMAs above keeps them after issue);
    // they retire on the LDS pipe while the matrix pipe drains beta's MFMAs.
    #pragma unroll
    for (int m = 0; m < 8; ++m) { af[m][0] = ldA(q, m, 0); af[m][1] = ldA(q, m, 1); }
    #pragma unroll
    for (int n = 0; n < 2; ++n) { b0[n][0] = ldB(q, n, 0); b0[n][1] = ldB(q, n, 1); }
    stageT(p, T + 2);   // safe: all reads-of-T done (alpha lgkm0 + BAR)
  }

  // epilogue: C row = brow*256 + m*32 + wr*16 + lhi*4 + j,
  //           C col = bcol*256 + n*64 + wc*16 + lr     [m89/m91 C/D map]
  const int crow0 = brow * 256 + wr * 16 + lhi * 4;
  const int ccol0 = bcol * 256 + wc * 16 + lr;
  if constexpr (MODE == 1) {
    // E = exp(sim) bf16 + per-block row-sum partials (deterministic)
    unsigned short* Cp = (unsigned short*)Cv;
    float rs[8][4];
    #pragma unroll
    for (int m = 0; m < 8; ++m)
      #pragma unroll
      for (int j = 0; j < 4; ++j) rs[m][j] = 0.f;
    #pragma unroll
    for (int m = 0; m < 8; ++m)
      #pragma unroll
      for (int n = 0; n < 4; ++n)
        #pragma unroll
        for (int j = 0; j < 4; ++j) {
          const float e = __expf(acc[m][n][j]);
          rs[m][j] += e;
          Cp[(size_t)(crow0 + m * 32 + j) * ldc + ccol0 + n * 64] = f2bf(e);
        }
    // 16-lane (lr) reduce -> lanes lr==0 hold this wave's 64-col sums
    #pragma unroll
    for (int m = 0; m < 8; ++m)
      #pragma unroll
      for (int j = 0; j < 4; ++j)
        #pragma unroll
        for (int o = 1; o < 16; o <<= 1) rs[m][j] += __shfl_xor(rs[m][j], o);
    VMC0();            // in-flight clamped stages still write smem
    __syncthreads();
    float* ls = (float*)smem;   // [wc][256 rows] = 4 KiB
    if (lr == 0) {
      #pragma unroll
      for (int m = 0; m < 8; ++m)
        #pragma unroll
        for (int j = 0; j < 4; ++j)
          ls[wc * 256 + wr * 16 + m * 32 + lhi * 4 + j] = rs[m][j];
    }
    __syncthreads();
    if (t < 256) {
      const float s4 = ls[t] + ls[256 + t] + ls[512 + t] + ls[768 + t];
      psum[(size_t)bcol * NB + brow * 256 + t] = s4;
    }
  } else {
    float* Cp = (float*)Cv + (unsigned long long)ksp * cstride;
    #pragma unroll
    for (int m = 0; m < 8; ++m)
      #pragma unroll
      for (int n = 0; n < 4; ++n)
        #pragma unroll
        for (int j = 0; j < 4; ++j)
          Cp[(size_t)(crow0 + m * 32 + j) * ldc + ccol0 + n * 64] = acc[m][n][j];
  }
}

// ---- scale: attn = E / s, s = sum of 32 col-block partials; also 1/s -------
__global__ void scale_kernel(const unsigned short* __restrict__ E,
                             const float* __restrict__ psum,
                             float* __restrict__ attn, float* __restrict__ sinv) {
  const int row = blockIdx.x, t = threadIdx.x;   // 256 thr
  __shared__ float sh;
  if (t < 64) {
    float p = (t < 32) ? psum[(size_t)t * NB + row] : 0.f;
    #pragma unroll
    for (int o = 16; o > 0; o >>= 1) p += __shfl_xor(p, o);
    if (t == 0) { sh = p; sinv[row] = 1.0f / p; }
  }
  __syncthreads();
  const float inv = 1.0f / sh;
  const unsigned short* erow = E + (size_t)row * NM;
  float* arow = attn + (size_t)row * NM;
  #pragma unroll
  for (int i = 0; i < 4; ++i) {
    u16x8 bv = ((const u16x8*)erow)[i * 256 + t];
    float4 f0, f1;
    #pragma unroll
    for (int j = 0; j < 8; ++j) {
      const float a = bf2f(bv[j]) * inv;
      if (j < 4) (&f0.x)[j] = a; else (&f1.x)[j - 4] = a;
    }
    const int e = (i * 256 + t) * 8;
    *(float4*)(arow + e) = f0;
    *(float4*)(arow + e + 4) = f1;
  }
}

// ---- reduce partials: mf = (sum_k part[k]) * sinv[row], S = 4 --------------
__global__ void reduce_kernel(const float4* __restrict__ part, float4* __restrict__ mf,
                              const float* __restrict__ sinv) {
  const size_t n4 = (size_t)NB * ND / 4;
  for (size_t i = (size_t)blockIdx.x * blockDim.x + threadIdx.x; i < n4;
       i += (size_t)gridDim.x * blockDim.x) {
    const float is = sinv[i >> 8];   // 256 float4 per row
    float4 s = part[i];
    #pragma unroll
    for (int k = 1; k < 4; ++k) {
      float4 p = part[(size_t)k * n4 + i];
      s.x += p.x; s.y += p.y; s.z += p.z; s.w += p.w;
    }
    s.x *= is; s.y *= is; s.z *= is; s.w *= is;
    mf[i] = s;
  }
}

extern "C" void kernel_launch(void* const* d_in, const int* in_sizes, int n_in,
                              void* d_out, int out_size, void* d_ws, size_t ws_size,
                              hipStream_t stream) {
  const float* q   = (const float*)d_in[0];
  const float* mem = (const float*)d_in[1];
  float* mf   = (float*)d_out;                       // [4096 x 1024]
  float* attn = (float*)d_out + (size_t)NB * ND;     // [4096 x 8192]
  char* ws = (char*)d_ws;
  unsigned short* qn   = (unsigned short*)(ws);                        // 8 MiB
  unsigned short* memn = (unsigned short*)(ws + ((size_t)8  << 20));   // 16 MiB
  unsigned short* memt = (unsigned short*)(ws + ((size_t)24 << 20));   // 16 MiB
  unsigned short* E    = (unsigned short*)(ws + ((size_t)40 << 20));   // 64 MiB
  float* psum          = (float*)(ws + ((size_t)104 << 20));           // 512 KiB
  float* sinv          = (float*)(ws + ((size_t)104 << 20) + (512 << 10)); // 16 KiB
  float* part          = (float*)(ws + ((size_t)105 << 20));           // 64 MiB

  hipFuncSetAttribute((const void*)gemm2p<1>,
                      hipFuncAttributeMaxDynamicSharedMemorySize, 131072);
  hipFuncSetAttribute((const void*)gemm2p<0>,
                      hipFuncAttributeMaxDynamicSharedMemorySize, 131072);

  hipLaunchKernelGGL(nrm_kernel, dim3(NM), dim3(256), 0, stream, mem, memn);
  hipLaunchKernelGGL(nrm_kernel, dim3(NB), dim3(256), 0, stream, q, qn);
  hipLaunchKernelGGL(tr_kernel, dim3(ND / 64, NM / 64), dim3(256), 0, stream, memn, memt);

  // E = exp(qn * memn^T) bf16 + psum : M=4096, N=8192, K=1024; 512 tiles.
  hipLaunchKernelGGL((gemm2p<1>), dim3((NB / 256) * (NM / 256)), dim3(512), 131072, stream,
                     qn, memn, (void*)E, psum, ND, NM, NB / 256,
                     (NB / 256) * (NM / 256), ND, 0ULL);

  // attn = E / s (fp32 out) + sinv
  hipLaunchKernelGGL(scale_kernel, dim3(NB), dim3(256), 0, stream, E, psum, attn, sinv);

  // part[k] = E * memt^T (k-slice) : M=4096, N=1024, K=8192, S=4 (kchunk 2048)
  const int tps = (NB / 256) * (ND / 256);   // 64
  hipLaunchKernelGGL((gemm2p<0>), dim3(tps * 4), dim3(512), 131072, stream,
                     E, memt, (void*)part, (float*)nullptr, NM, ND, NB / 256, tps, NM / 4,
                     (unsigned long long)NB * ND);
  hipLaunchKernelGGL(reduce_kernel, dim3(2048), dim3(256), 0, stream,
                     (const float4*)part, (float4*)mf, sinv);
}